// Round 11
// baseline (146.904 us; speedup 1.0000x reference)
//
#include <hip/hip_runtime.h>
#include <hip/hip_bf16.h>

typedef __attribute__((ext_vector_type(8))) short bf16x8;
typedef __attribute__((ext_vector_type(4))) float f32x4;
typedef __attribute__((ext_vector_type(4))) float fvec4;
typedef __attribute__((ext_vector_type(8))) unsigned short u16x8;

// B=4, T=256, U=64 -> M = 65536 rows; K(J)=512; N(V)=1024

__device__ __forceinline__ unsigned short f2bf(float f) {
  unsigned int u = __builtin_bit_cast(unsigned int, f);
  u += 0x7FFFu + ((u >> 16) & 1u);   // round-to-nearest-even
  return (unsigned short)(u >> 16);
}

__device__ __forceinline__ float fast_tanh(float x) {
  float cx = fminf(fmaxf(x, -9.0f), 9.0f);
  float e2 = __expf(cx + cx);
  return (e2 - 1.0f) * __builtin_amdgcn_rcpf(e2 + 1.0f);
}

// ---- fused prep: enc-proj (blocks 0..127), pred-proj (128..159), W_out^T (160..287)

__device__ __forceinline__ void proj_body(
    const float* __restrict__ x, const float* __restrict__ W,
    const float* __restrict__ bias, float* __restrict__ out,
    int blk, uint8_t* sh) {
  float (*xt)[9] = (float (*)[9])sh;   // [256][9] f32 = 9216 B
  const int tid = threadIdx.x;
  const int row0 = blk << 3;
  #pragma unroll
  for (int i = 0; i < 8; ++i)
    xt[tid][i] = x[(size_t)(row0 + i) * 256 + tid];
  __syncthreads();
  float acc0[8] = {0.f,0.f,0.f,0.f,0.f,0.f,0.f,0.f};
  float acc1[8] = {0.f,0.f,0.f,0.f,0.f,0.f,0.f,0.f};
  #pragma unroll 4
  for (int k = 0; k < 256; ++k) {
    float w0 = W[(size_t)k * 512 + tid];
    float w1 = W[(size_t)k * 512 + tid + 256];
    #pragma unroll
    for (int r = 0; r < 8; ++r) {
      float xv = xt[k][r];
      acc0[r] = fmaf(xv, w0, acc0[r]);
      acc1[r] = fmaf(xv, w1, acc1[r]);
    }
  }
  float b0 = bias[tid], b1 = bias[tid + 256];
  #pragma unroll
  for (int r = 0; r < 8; ++r) {
    out[(size_t)(row0 + r) * 512 + tid]       = acc0[r] + b0;
    out[(size_t)(row0 + r) * 512 + tid + 256] = acc1[r] + b1;
  }
}

// W_out [512 k][1024 n] f32 -> Bt2 K-MAJOR bf16: index =
//   (n>>9)*262144 + (k>>5)*16384 + (n&511)*32 + (k&31)
// -> a register B-frag load (16 n-rows x 8 k) is ONE contiguous 1 KiB segment.
__device__ __forceinline__ void transpose_body(
    const float* __restrict__ W, unsigned short* __restrict__ Bt2,
    int blk, uint8_t* sh) {
  unsigned short (*tile)[65] = (unsigned short (*)[65])sh;  // [64 k][65 n]
  const int k0 = (blk & 7) << 6;
  const int n0 = (blk >> 3) << 6;
  const int tid = threadIdx.x;
  #pragma unroll
  for (int i = 0; i < 16; ++i) {
    int idx = tid + (i << 8);
    int r = idx >> 6, c = idx & 63;        // r = k-off, c = n-off (coalesced read)
    tile[r][c] = f2bf(W[(size_t)(k0 + r) * 1024 + n0 + c]);
  }
  __syncthreads();
  #pragma unroll
  for (int i = 0; i < 16; ++i) {
    int idx = tid + (i << 8);
    int r = idx >> 6, c = idx & 63;        // r = n-off, c = k-off
    int ng = n0 + r, kg = k0 + c;
    size_t dst = ((size_t)(ng >> 9) << 18) + ((size_t)(kg >> 5) << 14)
               + ((ng & 511) << 5) + (kg & 31);
    Bt2[dst] = tile[c][r];
  }
}

__global__ __launch_bounds__(256) void prep_kernel(
    const float* __restrict__ enc, const float* __restrict__ We,
    const float* __restrict__ be, float* __restrict__ encp,
    const float* __restrict__ pred, const float* __restrict__ Wd,
    const float* __restrict__ bd, float* __restrict__ predp,
    const float* __restrict__ Wo, unsigned short* __restrict__ Bt2) {
  __shared__ uint8_t sh[9216];
  const int b = blockIdx.x;
  if (b < 128)       proj_body(enc, We, be, encp, b, sh);
  else if (b < 160)  proj_body(pred, Wd, bd, predp, b - 128, sh);
  else               transpose_body(Wo, Bt2, b - 160, sh);
}

// ---- fused joint+gemm, round 11: BM=128 (was 64), BN=512, K=512.
// SINGLE change vs r10: halve B L2/L1 traffic (1 GiB -> 512 MiB) by doubling BM.
// 1024 threads, 16 waves (2m x 8n), per-wave 64x64 (K-loop step body identical
// to r10).  A = full 128x512 bf16 = 128 KiB LDS, XOR-swizzled, built once ->
// K-loop stays BARRIER-FREE (no r9-style mid-loop rebuild; tanh total
// unchanged at 2x).  1 block/CU x 16 waves = same waves/CU as r10's 2x8.
// Epilogue: single region reusing dead A space, raw lgkm barriers (no vmcnt
// drain), nontemporal contiguous 1 KiB stores.
__global__ __launch_bounds__(1024, 4) void fused_gemm(
    const float* __restrict__ encp, const float* __restrict__ predp,
    const unsigned short* __restrict__ Bt2, const float* __restrict__ bout,
    float* __restrict__ out) {
  __shared__ uint8_t lds[131072];   // A: [128][512 bf16] swz; epi (reuse): [32][516] f32
  const int tid = threadIdx.x;
  const int lane = tid & 63, wid = tid >> 6;
  const int fr = lane & 15, fg = lane >> 4;
  const int wm = wid >> 3, wn = wid & 7;      // 2m x 8n wave grid
  const int b = blockIdx.x;
  const int wg = ((b & 7) << 7) + (b >> 3);   // XCD swizzle, 1024 % 8 == 0 (bijective)
  const int mt = wg >> 1, half = wg & 1;      // half inner: pair shares A rows
  const int m0 = mt << 7;
  const int cb0 = half << 9;

  // per-lane B base in K-major layout: elem = (kt<<14) + (n<<5) + (fg<<3),
  // n = wn*64 + nf*16 + fr.  frag nf offset = nf<<9; kt offset = kt<<14.
  const unsigned short* Bgl =
      Bt2 + ((size_t)half << 18) + (((wn << 6) + fr) << 5) + (fg << 3);

  bf16x8 bA[4], bB[4];
  #pragma unroll
  for (int nf = 0; nf < 4; ++nf)      // issue tile-0 B loads before tanh phase
    bA[nf] = *(const bf16x8*)(Bgl + (nf << 9));

  // ---- phase 0: A tile (128 rows x 512 k) -> swizzled LDS.
  // f(row,chunk) = row*1024 + ((chunk^(row&7))<<4)
  {
    const int r = tid >> 3, cb = tid & 7;    // r 0..127, cb 0..7
    const float* erow = encp + (((size_t)(mt << 1) + (r >> 6)) << 9);
    const float* prow = predp + ((size_t)(((mt >> 7) << 6) + (r & 63)) << 9);
    uint8_t* rowbase = lds + (r << 10);
    #pragma unroll
    for (int c8 = 0; c8 < 8; ++c8) {
      int chunk = cb + (c8 << 3);
      int k8 = chunk << 3;
      fvec4 e0 = *(const fvec4*)(erow + k8);
      fvec4 e1 = *(const fvec4*)(erow + k8 + 4);
      fvec4 p0 = *(const fvec4*)(prow + k8);
      fvec4 p1 = *(const fvec4*)(prow + k8 + 4);
      u16x8 o;
      #pragma unroll
      for (int i = 0; i < 4; ++i) o[i]     = f2bf(fast_tanh(e0[i] + p0[i]));
      #pragma unroll
      for (int i = 0; i < 4; ++i) o[i + 4] = f2bf(fast_tanh(e1[i] + p1[i]));
      *(u16x8*)(rowbase + ((chunk ^ (r & 7)) << 4)) = o;
    }
  }
  asm volatile("s_waitcnt lgkmcnt(0)" ::: "memory");
  __builtin_amdgcn_s_barrier();   // A published; K-loop below is barrier-free

  f32x4 acc[4][4];
  f32x4 zero4 = {0.f, 0.f, 0.f, 0.f};
  #pragma unroll
  for (int i = 0; i < 4; ++i)
    #pragma unroll
    for (int j = 0; j < 4; ++j) acc[i][j] = zero4;

  // A read addr: row = wm*64 + mf*16 + fr; chunk = ((kt<<2)|fg) ^ (fr&7)
  //            = ((kt^qh)<<2) | (fg^(fr&3)),  qh = (fr>>2)&1
  const int qh = (fr >> 2) & 1;
  int arow[4];
  #pragma unroll
  for (int mf = 0; mf < 4; ++mf)
    arow[mf] = (((wm << 6) + (mf << 4) + fr) << 10) + ((fg ^ (fr & 3)) << 4);

  // one K-step: prefetch B(kt+1) into nxt (contiguous 1KiB/instr), read A frags
  // from LDS, 16 MFMA on cur.  No barriers, no LDS writes.
  auto step = [&](int kt, bf16x8 (&cur)[4], bf16x8 (&nxt)[4]) {
    const int ktn = kt < 15 ? kt + 1 : 15;   // last iter: harmless dup reload
    #pragma unroll
    for (int nf = 0; nf < 4; ++nf)
      nxt[nf] = *(const bf16x8*)(Bgl + (ktn << 14) + (nf << 9));
    const int ko = (kt ^ qh) << 6;
    bf16x8 af[4];
    #pragma unroll
    for (int mf = 0; mf < 4; ++mf)
      af[mf] = *(const bf16x8*)(lds + arow[mf] + ko);
    #pragma unroll
    for (int mf = 0; mf < 4; ++mf)
      #pragma unroll
      for (int nf = 0; nf < 4; ++nf)
        acc[mf][nf] = __builtin_amdgcn_mfma_f32_16x16x32_bf16(cur[nf], af[mf],
                                                              acc[mf][nf], 0, 0, 0);
  };

  #pragma unroll
  for (int kt = 0; kt < 16; kt += 2) {   // static ping-pong (rule #20)
    step(kt,     bA, bB);
    step(kt + 1, bB, bA);
  }

  // ---- epilogue: single region [32][516] f32 in dead A space; raw lgkm
  // barriers only (stores never waited on).  4 rounds (one per mf):
  //   barrier (region's prior readers done / K-loop A reads done)
  //   deposit acc+bias (rows wm*16+fr, cols wn*64+nf*16+fg*4)
  //   barrier (deposits visible)
  //   drain: idx = wid*4+j -> row idx>>1, seg idx&1; 1 KiB contiguous
  //   nontemporal store per instr.
  float (*epi)[516] = (float (*)[516])lds;
  const int colw = (wn << 6) + (fg << 2);
  fvec4 bvv[4];
  #pragma unroll
  for (int nf = 0; nf < 4; ++nf)
    bvv[nf] = *(const fvec4*)&bout[cb0 + colw + (nf << 4)];

  const int drow = (wm << 4) + fr;   // deposit row 0..31
  #pragma unroll
  for (int mf = 0; mf < 4; ++mf) {
    asm volatile("s_waitcnt lgkmcnt(0)" ::: "memory");
    __builtin_amdgcn_s_barrier();
    #pragma unroll
    for (int nf = 0; nf < 4; ++nf) {
      fvec4 o = acc[mf][nf] + bvv[nf];
      *(fvec4*)&epi[drow][colw + (nf << 4)] = o;
    }
    asm volatile("s_waitcnt lgkmcnt(0)" ::: "memory");
    __builtin_amdgcn_s_barrier();
    #pragma unroll
    for (int j = 0; j < 4; ++j) {
      const int idx = (wid << 2) + j;            // 0..63
      const int row = idx >> 1, seg = idx & 1;   // 32 rows x 2 segs
      fvec4 v = *(const fvec4*)&epi[row][(seg << 8) + (lane << 2)];
      const int gm = m0 + ((row >> 4) << 6) + (mf << 4) + (row & 15);
      __builtin_nontemporal_store(
          v, (fvec4*)&out[(size_t)gm * 1024 + cb0 + (seg << 8) + (lane << 2)]);
    }
  }
}

extern "C" void kernel_launch(void* const* d_in, const int* in_sizes, int n_in,
                              void* d_out, int out_size, void* d_ws, size_t ws_size,
                              hipStream_t stream) {
  const float* enc   = (const float*)d_in[0];
  const float* pred  = (const float*)d_in[1];
  const float* W_enc = (const float*)d_in[2];
  const float* b_enc = (const float*)d_in[3];
  const float* W_dec = (const float*)d_in[4];
  const float* b_dec = (const float*)d_in[5];
  const float* W_out = (const float*)d_in[6];
  const float* b_out = (const float*)d_in[7];
  float* out = (float*)d_out;

  uint8_t* ws = (uint8_t*)d_ws;
  float* encp  = (float*)ws;                           // [1024][512] f32, 2 MiB
  float* predp = (float*)(ws + 2097152);               // [256][512]  f32, 0.5 MiB
  unsigned short* bt2 = (unsigned short*)(ws + 2621440);// K-major W_out^T bf16, 1 MiB

  prep_kernel<<<288, 256, 0, stream>>>(enc, W_enc, b_enc, encp,
                                       pred, W_dec, b_dec, predp,
                                       W_out, bt2);
  fused_gemm<<<1024, 1024, 0, stream>>>(encp, predp, bt2, b_out, out);
}

// Round 12
// 126.322 us; speedup vs baseline: 1.1629x; 1.1629x over previous
//
#include <hip/hip_runtime.h>
#include <hip/hip_bf16.h>

typedef __attribute__((ext_vector_type(8))) short bf16x8;
typedef __attribute__((ext_vector_type(4))) float fvec4;
typedef __attribute__((ext_vector_type(16))) float f32x16;
typedef __attribute__((ext_vector_type(8))) unsigned short u16x8;

// B=4, T=256, U=64 -> M = 65536 rows; K(J)=512; N(V)=1024

__device__ __forceinline__ unsigned short f2bf(float f) {
  unsigned int u = __builtin_bit_cast(unsigned int, f);
  u += 0x7FFFu + ((u >> 16) & 1u);   // round-to-nearest-even
  return (unsigned short)(u >> 16);
}

__device__ __forceinline__ float fast_tanh(float x) {
  float cx = fminf(fmaxf(x, -9.0f), 9.0f);
  float e2 = __expf(cx + cx);
  return (e2 - 1.0f) * __builtin_amdgcn_rcpf(e2 + 1.0f);
}

// ---- fused prep: enc-proj (blocks 0..127), pred-proj (128..159), W_out^T (160..287)

__device__ __forceinline__ void proj_body(
    const float* __restrict__ x, const float* __restrict__ W,
    const float* __restrict__ bias, float* __restrict__ out,
    int blk, uint8_t* sh) {
  float (*xt)[9] = (float (*)[9])sh;   // [256][9] f32 = 9216 B
  const int tid = threadIdx.x;
  const int row0 = blk << 3;
  #pragma unroll
  for (int i = 0; i < 8; ++i)
    xt[tid][i] = x[(size_t)(row0 + i) * 256 + tid];
  __syncthreads();
  float acc0[8] = {0.f,0.f,0.f,0.f,0.f,0.f,0.f,0.f};
  float acc1[8] = {0.f,0.f,0.f,0.f,0.f,0.f,0.f,0.f};
  #pragma unroll 4
  for (int k = 0; k < 256; ++k) {
    float w0 = W[(size_t)k * 512 + tid];
    float w1 = W[(size_t)k * 512 + tid + 256];
    #pragma unroll
    for (int r = 0; r < 8; ++r) {
      float xv = xt[k][r];
      acc0[r] = fmaf(xv, w0, acc0[r]);
      acc1[r] = fmaf(xv, w1, acc1[r]);
    }
  }
  float b0 = bias[tid], b1 = bias[tid + 256];
  #pragma unroll
  for (int r = 0; r < 8; ++r) {
    out[(size_t)(row0 + r) * 512 + tid]       = acc0[r] + b0;
    out[(size_t)(row0 + r) * 512 + tid + 256] = acc1[r] + b1;
  }
}

// W_out [512 k][1024 n] f32 -> Bt3 K16-sliced bf16:
//   dst = (n>>9)<<18 | (k>>4)<<13 | (n&511)<<4 | (k&15)
// -> one 32x32x16 B-frag (32 n-rows x 8 k halves) = ONE contiguous 1 KiB segment.
__device__ __forceinline__ void transpose_body(
    const float* __restrict__ W, unsigned short* __restrict__ Bt3,
    int blk, uint8_t* sh) {
  unsigned short (*tile)[65] = (unsigned short (*)[65])sh;  // [64 k][65 n]
  const int k0 = (blk & 7) << 6;
  const int n0 = (blk >> 3) << 6;
  const int tid = threadIdx.x;
  #pragma unroll
  for (int i = 0; i < 16; ++i) {
    int idx = tid + (i << 8);
    int r = idx >> 6, c = idx & 63;        // r = k-off, c = n-off (coalesced read)
    tile[r][c] = f2bf(W[(size_t)(k0 + r) * 1024 + n0 + c]);
  }
  __syncthreads();
  #pragma unroll
  for (int i = 0; i < 16; ++i) {
    int idx = tid + (i << 8);
    int r = idx >> 6, c = idx & 63;        // r = n-off, c = k-off
    int ng = n0 + r, kg = k0 + c;
    size_t dst = ((size_t)(ng >> 9) << 18) + ((size_t)(kg >> 4) << 13)
               + ((ng & 511) << 4) + (kg & 15);
    Bt3[dst] = tile[c][r];
  }
}

__global__ __launch_bounds__(256) void prep_kernel(
    const float* __restrict__ enc, const float* __restrict__ We,
    const float* __restrict__ be, float* __restrict__ encp,
    const float* __restrict__ pred, const float* __restrict__ Wd,
    const float* __restrict__ bd, float* __restrict__ predp,
    const float* __restrict__ Wo, unsigned short* __restrict__ Bt3) {
  __shared__ uint8_t sh[9216];
  const int b = blockIdx.x;
  if (b < 128)       proj_body(enc, We, be, encp, b, sh);
  else if (b < 160)  proj_body(pred, Wd, bd, predp, b - 128, sh);
  else               transpose_body(Wo, Bt3, b - 160, sh);
}

// ---- fused joint+gemm (r10 skeleton, r12: 32x32x16 MFMA):
// BM=64, BN=512, K=512, 8 waves x (64M x 64N), 2 blocks/CU.
//  * A = bf16(tanh(encp+predp)) once into 64 KiB LDS, chunk ^= (row&15) swizzle
//    (bank-optimal for 32-row frag reads) -> K-loop barrier-free.
//  * B-frags direct to regs from K16-sliced Bt3 (contiguous 1 KiB/load),
//    register ping-pong prefetch depth 1; 32 K-steps of K=16.
//  * mfma_f32_32x32x16_bf16, operands swapped: lane holds C[m=lane&31]
//    [n = (reg&3)+4*(lane>>5)+8*(reg>>2) within 32-col frag] -> fvec4 deposits.
//  * epilogue: 2 rounds (ma=0,1), region [32][516] f32 in dead A space, raw
//    lgkm barriers only, contiguous 1 KiB nontemporal stores (never waited).
__global__ __launch_bounds__(512, 4) void fused_gemm(
    const float* __restrict__ encp, const float* __restrict__ predp,
    const unsigned short* __restrict__ Bt3, const float* __restrict__ bout,
    float* __restrict__ out) {
  __shared__ uint8_t lds[66560];   // A: [64][512 bf16] swz; epi (reuse): [32][516] f32
  const int tid = threadIdx.x;
  const int lane = tid & 63, wid = tid >> 6;
  const int l31 = lane & 31, hi = lane >> 5;
  const int b = blockIdx.x;
  const int wg = ((b & 7) << 8) + (b >> 3);   // XCD swizzle, 2048 % 8 == 0 (bijective)
  const int mt = wg >> 1, half = wg & 1;      // half inner: pair shares A rows
  const int m0 = mt << 6;
  const int cb0 = half << 9;

  // per-lane B base: slice (half, kt16) + row n*16 elems + hi*8
  // n = wid*64 + na*32 + l31;  na step = 1<<9 elems; kt step = 1<<13 elems.
  const unsigned short* Bgl =
      Bt3 + ((size_t)half << 18) + (((wid << 6) + l31) << 4) + (hi << 3);

  bf16x8 bA[2], bB[2];
  #pragma unroll
  for (int na = 0; na < 2; ++na)     // kt=0 loads issued before tanh phase
    bA[na] = *(const bf16x8*)(Bgl + (na << 9));

  // ---- phase 0: A tile -> swizzled LDS. f(row,chunk)=row*1024+((chunk^(row&15))<<4)
  {
    const int r = tid >> 3, cb = tid & 7;
    const float* erow = encp + ((size_t)mt << 9);
    const float* prow = predp + ((size_t)(((mt >> 8) << 6) + r) << 9);
    uint8_t* rowbase = lds + (r << 10);
    #pragma unroll
    for (int c8 = 0; c8 < 8; ++c8) {
      int chunk = cb + (c8 << 3);
      int k8 = chunk << 3;
      fvec4 e0 = *(const fvec4*)(erow + k8);
      fvec4 e1 = *(const fvec4*)(erow + k8 + 4);
      fvec4 p0 = *(const fvec4*)(prow + k8);
      fvec4 p1 = *(const fvec4*)(prow + k8 + 4);
      u16x8 o;
      #pragma unroll
      for (int i = 0; i < 4; ++i) o[i]     = f2bf(fast_tanh(e0[i] + p0[i]));
      #pragma unroll
      for (int i = 0; i < 4; ++i) o[i + 4] = f2bf(fast_tanh(e1[i] + p1[i]));
      *(u16x8*)(rowbase + ((chunk ^ (r & 15)) << 4)) = o;
    }
  }
  asm volatile("s_waitcnt lgkmcnt(0)" ::: "memory");
  __builtin_amdgcn_s_barrier();   // A published; K-loop below is barrier-free

  f32x16 acc[2][2];
  #pragma unroll
  for (int i = 0; i < 2; ++i)
    #pragma unroll
    for (int j = 0; j < 2; ++j)
      #pragma unroll
      for (int e = 0; e < 16; ++e) acc[i][j][e] = 0.f;

  // A frag read: row = ma*32 + l31 (1 KiB stride); chunk = (kt<<1)|hi, swizzled
  // chunk' = chunk ^ (lane&15) = (kt<<1) ^ hx,  hx = hi ^ (lane&15)
  const int hx = hi ^ (lane & 15);
  int arowb[2];
  #pragma unroll
  for (int ma = 0; ma < 2; ++ma)
    arowb[ma] = ((ma << 5) + l31) << 10;

  // one K16-step: prefetch B(kt+1) into nxt, read 2 A frags, 4 MFMA on cur
  auto step = [&](int kt, bf16x8 (&cur)[2], bf16x8 (&nxt)[2]) {
    const int ktn = kt < 31 ? kt + 1 : 31;   // last iter: harmless dup reload
    #pragma unroll
    for (int na = 0; na < 2; ++na)
      nxt[na] = *(const bf16x8*)(Bgl + (ktn << 13) + (na << 9));
    const int ao = (((kt << 1) ^ hx) << 4);
    bf16x8 af[2];
    #pragma unroll
    for (int ma = 0; ma < 2; ++ma)
      af[ma] = *(const bf16x8*)(lds + arowb[ma] + ao);
    #pragma unroll
    for (int ma = 0; ma < 2; ++ma)
      #pragma unroll
      for (int na = 0; na < 2; ++na)
        acc[ma][na] = __builtin_amdgcn_mfma_f32_32x32x16_bf16(
            cur[na], af[ma], acc[ma][na], 0, 0, 0);
  };

  #pragma unroll
  for (int kt = 0; kt < 32; kt += 2) {   // static ping-pong (rule #20)
    step(kt,     bA, bB);
    step(kt + 1, bB, bA);
  }

  // ---- epilogue: 2 rounds (ma), region [32][516] f32 in dead A space.
  // Deposit: lane l: row l31; cols wid*64 + na*32 + q*8 + hi*4 (+j) for reg 4q+j.
  float (*epi)[516] = (float (*)[516])lds;
  fvec4 bvv[2][4];
  #pragma unroll
  for (int na = 0; na < 2; ++na)
    #pragma unroll
    for (int q = 0; q < 4; ++q)
      bvv[na][q] = *(const fvec4*)&bout[cb0 + (wid << 6) + (na << 5) +
                                       (q << 3) + (hi << 2)];

  #pragma unroll
  for (int ma = 0; ma < 2; ++ma) {
    asm volatile("s_waitcnt lgkmcnt(0)" ::: "memory");
    __builtin_amdgcn_s_barrier();   // K-loop A reads / prev round reads done
    #pragma unroll
    for (int na = 0; na < 2; ++na)
      #pragma unroll
      for (int q = 0; q < 4; ++q) {
        fvec4 o;
        #pragma unroll
        for (int j = 0; j < 4; ++j) o[j] = acc[ma][na][(q << 2) + j] + bvv[na][q][j];
        *(fvec4*)&epi[l31][(wid << 6) + (na << 5) + (q << 3) + (hi << 2)] = o;
      }
    asm volatile("s_waitcnt lgkmcnt(0)" ::: "memory");
    __builtin_amdgcn_s_barrier();   // deposits visible
    #pragma unroll
    for (int j = 0; j < 8; ++j) {
      const int idx = (wid << 3) + j;            // 0..63
      const int row = idx >> 1, seg = idx & 1;   // 32 rows x 2 segs
      fvec4 v = *(const fvec4*)&epi[row][(seg << 8) + (lane << 2)];
      const int gm = m0 + (ma << 5) + row;
      __builtin_nontemporal_store(
          v, (fvec4*)&out[(size_t)gm * 1024 + cb0 + (seg << 8) + (lane << 2)]);
    }
  }
}

extern "C" void kernel_launch(void* const* d_in, const int* in_sizes, int n_in,
                              void* d_out, int out_size, void* d_ws, size_t ws_size,
                              hipStream_t stream) {
  const float* enc   = (const float*)d_in[0];
  const float* pred  = (const float*)d_in[1];
  const float* W_enc = (const float*)d_in[2];
  const float* b_enc = (const float*)d_in[3];
  const float* W_dec = (const float*)d_in[4];
  const float* b_dec = (const float*)d_in[5];
  const float* W_out = (const float*)d_in[6];
  const float* b_out = (const float*)d_in[7];
  float* out = (float*)d_out;

  uint8_t* ws = (uint8_t*)d_ws;
  float* encp  = (float*)ws;                           // [1024][512] f32, 2 MiB
  float* predp = (float*)(ws + 2097152);               // [256][512]  f32, 0.5 MiB
  unsigned short* bt3 = (unsigned short*)(ws + 2621440);// K16-sliced W_out^T bf16, 1 MiB

  prep_kernel<<<288, 256, 0, stream>>>(enc, W_enc, b_enc, encp,
                                       pred, W_dec, b_dec, predp,
                                       W_out, bt3);
  fused_gemm<<<2048, 512, 0, stream>>>(encp, predp, bt3, b_out, out);
}